// Round 2
// baseline (99.045 us; speedup 1.0000x reference)
//
#include <hip/hip_runtime.h>
#include <hip/hip_bf16.h>
#include <stdint.h>

#define LOG2E 1.4426950408889634f

typedef __attribute__((ext_vector_type(4))) float f4;
typedef __attribute__((ext_vector_type(4))) int   i4;
typedef __attribute__((ext_vector_type(8))) short s8;   // 8 x bf16
typedef __attribute__((ext_vector_type(4))) short s4;   // 4 x bf16

#if defined(__has_builtin)
# if __has_builtin(__builtin_amdgcn_exp2f)
#  define EXP2F(x) __builtin_amdgcn_exp2f(x)
# else
#  define EXP2F(x) exp2f(x)
# endif
#else
# define EXP2F(x) exp2f(x)
#endif

static __device__ __forceinline__ uint32_t fbits(float f) {
  union { float f; uint32_t u; } c; c.f = f; return c.u;
}
static __device__ __forceinline__ float ubits(uint32_t u) {
  union { uint32_t u; float f; } c; c.u = u; return c.f;
}
static __device__ __forceinline__ uint16_t bf16_rne(float f) {
  uint32_t b = fbits(f);
  b += 0x7FFFu + ((b >> 16) & 1u);
  return (uint16_t)(b >> 16);
}
static __device__ __forceinline__ float bf2f(uint16_t u) {
  return ubits(((uint32_t)u) << 16);
}
// order-preserving float->uint key (for atomicMax on floats)
static __device__ __forceinline__ uint32_t fkey(float f) {
  uint32_t u = fbits(f);
  return (u >> 31) ? ~u : (u | 0x80000000u);
}
static __device__ __forceinline__ float unkey(uint32_t k) {
  return ubits((k & 0x80000000u) ? (k ^ 0x80000000u) : ~k);
}

// ---- K1: W (H,256,64) f32 -> WT (H,64,256) bf16; init f2max keys ----
__global__ __launch_bounds__(256) void k_prep_wt(const float* __restrict__ W,
                                                 uint16_t* __restrict__ WT,
                                                 uint32_t* __restrict__ f2mkey) {
  if (blockIdx.x == 0 && threadIdx.x < 4) f2mkey[threadIdx.x] = 0u;
  int idx = (blockIdx.x * 256 + threadIdx.x) * 4;   // 65536 elems, grid 64
  f4 w = *(const f4*)(W + idx);
  int h = idx >> 14;
  int k = (idx >> 6) & 255;
  int o = idx & 63;
  uint16_t* base = WT + ((h << 6) + o) * 256 + k;
  base[0]   = bf16_rne(w.x);
  base[256] = bf16_rne(w.y);
  base[512] = bf16_rne(w.z);
  base[768] = bf16_rne(w.w);
}

// ------- K2: h = x @ W per head (MFMA), fused f1/f2 + f2max + hT store -----
__global__ __launch_bounds__(256) void k_gemm_h(
    const float* __restrict__ x, const uint16_t* __restrict__ WT,
    const float* __restrict__ a,
    uint16_t* __restrict__ hT, float* __restrict__ f1, float* __restrict__ f2,
    uint32_t* __restrict__ f2mkey) {
  const int N = 4096, K = 256;
  __shared__ uint16_t xs[16][264];
  int t = threadIdx.x;
  int i0 = blockIdx.x * 16;
  {
    int r = t >> 4, c = (t & 15) << 4;
    const float* src = x + (i0 + r) * K + c;
    union { uint16_t u[16]; s8 v[2]; } tmp;
    #pragma unroll
    for (int i = 0; i < 16; i += 4) {
      f4 v = *(const f4*)(src + i);
      tmp.u[i+0] = bf16_rne(v.x); tmp.u[i+1] = bf16_rne(v.y);
      tmp.u[i+2] = bf16_rne(v.z); tmp.u[i+3] = bf16_rne(v.w);
    }
    *(s8*)&xs[r][c]     = tmp.v[0];
    *(s8*)&xs[r][c + 8] = tmp.v[1];
  }
  __syncthreads();
  int wave = t >> 6, lane = t & 63, lr = lane & 15, lc = lane >> 4;
  f4 acc[4];
  #pragma unroll
  for (int cg = 0; cg < 4; ++cg) acc[cg] = (f4){0.f, 0.f, 0.f, 0.f};
  #pragma unroll
  for (int ks = 0; ks < 8; ++ks) {
    s8 af = *(const s8*)&xs[lr][ks * 32 + lc * 8];
    #pragma unroll
    for (int cg = 0; cg < 4; ++cg) {
      s8 bf = *(const s8*)(WT + ((wave << 6) + (cg << 4) + lr) * 256 + ks * 32 + lc * 8);
      acc[cg] = __builtin_amdgcn_mfma_f32_16x16x32_bf16(af, bf, acc[cg], 0, 0, 0);
    }
  }
  float p1[4] = {0, 0, 0, 0}, p2[4] = {0, 0, 0, 0};
  #pragma unroll
  for (int cg = 0; cg < 4; ++cg) {
    float a1v = a[wave * 128 + (cg << 4) + lr];
    float a2v = a[wave * 128 + 64 + (cg << 4) + lr];
    #pragma unroll
    for (int q = 0; q < 4; ++q) {
      p1[q] = fmaf(acc[cg][q], a1v, p1[q]);
      p2[q] = fmaf(acc[cg][q], a2v, p2[q]);
    }
  }
  #pragma unroll
  for (int m = 1; m <= 8; m <<= 1) {
    #pragma unroll
    for (int q = 0; q < 4; ++q) {
      p1[q] += __shfl_xor(p1[q], m, 64);
      p2[q] += __shfl_xor(p2[q], m, 64);
    }
  }
  if (lr == 0) {
    #pragma unroll
    for (int q = 0; q < 4; ++q) {
      f1[wave * N + i0 + (lc << 2) + q] = p1[q];
      f2[wave * N + i0 + (lc << 2) + q] = p2[q];
    }
  }
  // fused per-head f2 max -> atomicMax on order-preserving key
  float wm = fmaxf(fmaxf(p2[0], p2[1]), fmaxf(p2[2], p2[3]));
  wm = fmaxf(wm, __shfl_xor(wm, 16, 64));
  wm = fmaxf(wm, __shfl_xor(wm, 32, 64));
  if (lane == 0) atomicMax(&f2mkey[wave], fkey(wm));
  // hT[h][o][n] bf16
  #pragma unroll
  for (int cg = 0; cg < 4; ++cg) {
    union { uint16_t u[4]; s4 v; } h4;
    #pragma unroll
    for (int q = 0; q < 4; ++q) h4.u[q] = bf16_rne(acc[cg][q]);
    *(s4*)(hT + (size_t)((wave << 6) + (cg << 4) + lr) * N + i0 + (lc << 2)) = h4.v;
  }
}

// -------- K4: flash partial, direct-global adj, no LDS, no barriers --------
__global__ __launch_bounds__(256) void k_attn(
    const int* __restrict__ adj, const float* __restrict__ f1,
    const float* __restrict__ f2, const uint32_t* __restrict__ f2mkey,
    const uint16_t* __restrict__ hT,
    uint16_t* __restrict__ Op, float* __restrict__ lp, int NP) {
  const int N = 4096;
  int p = blockIdx.x % NP;          // == XCD id when NP==8 (L2 locality for hT/f2 slice)
  int rb = blockIdx.x / NP;
  int i0 = rb << 5;                 // 32 rows per block
  int jcount = N / NP, jbase = p * jcount, ntiles = jcount >> 6;
  int t = threadIdx.x, wave = t >> 6, lane = t & 63, lr = lane & 15, lc = lane >> 4;

  float fm = unkey(f2mkey[wave]);
  float d1[2], d2[2], lsum[2] = {0.f, 0.f};
  #pragma unroll
  for (int g = 0; g < 2; ++g) {
    float f1v = f1[wave * N + i0 + (g << 4) + lr];
    float s = f1v + fm;
    float M = fmaxf(s, 0.2f * s);               // static per-row upper bound
    d1[g] = fmaf(f1v, LOG2E, -M * LOG2E);
    d2[g] = fmaf(f1v, 0.2f * LOG2E, -M * LOG2E);
  }
  f4 acc[2][4];
  #pragma unroll
  for (int g = 0; g < 2; ++g)
    #pragma unroll
    for (int cg = 0; cg < 4; ++cg) acc[g][cg] = (f4){0.f, 0.f, 0.f, 0.f};

  const int* asrc = adj + (size_t)(i0 + lr) * N + jbase + (lc << 3);
  const uint16_t* hTb = hT + (size_t)((wave << 6) + lr) * N + jbase + (lc << 3);
  const float* f2b = f2 + wave * N + jbase + (lc << 3);

  #pragma unroll 2
  for (int tile = 0; tile < ntiles; ++tile) {
    #pragma unroll
    for (int ks = 0; ks < 2; ++ks) {
      int joff = tile * 64 + (ks << 5);
      f4 f2v0 = *(const f4*)(f2b + joff);
      f4 f2v1 = *(const f4*)(f2b + joff + 4);
      s8 bf[4];
      #pragma unroll
      for (int cg = 0; cg < 4; ++cg)
        bf[cg] = *(const s8*)(hTb + (size_t)(cg << 4) * N + joff);
      #pragma unroll
      for (int g = 0; g < 2; ++g) {
        const int* ap = asrc + (size_t)(g << 4) * N + joff;
        i4 a0 = *(const i4*)ap;
        i4 a1 = *(const i4*)(ap + 4);
        float pe[8];
        #pragma unroll
        for (int e = 0; e < 8; ++e) {
          float f2e = (e < 4) ? f2v0[e] : f2v1[e - 4];
          int   ai  = (e < 4) ? a0[e]   : a1[e - 4];
          float arg = fmaxf(fmaf(f2e, LOG2E, d1[g]),
                            fmaf(f2e, 0.2f * LOG2E, d2[g]));
          float pv = ai ? EXP2F(arg) : 0.f;   // mask via cndmask
          lsum[g] += pv;
          pe[e] = pv;
        }
        union { uint32_t u[4]; s8 v; } af;
        #pragma unroll
        for (int i = 0; i < 4; ++i)
          af.u[i] = __builtin_amdgcn_perm(fbits(pe[2 * i + 1]) + 0x8000u,
                                          fbits(pe[2 * i]) + 0x8000u,
                                          0x07060302u);
        #pragma unroll
        for (int cg = 0; cg < 4; ++cg)
          acc[g][cg] = __builtin_amdgcn_mfma_f32_16x16x32_bf16(af.v, bf[cg],
                                                               acc[g][cg], 0, 0, 0);
      }
    }
  }
  // store partials
  uint16_t* ob = Op + (size_t)((p << 2) + wave) * N * 64 + (size_t)i0 * 64;
  #pragma unroll
  for (int g = 0; g < 2; ++g) {
    #pragma unroll
    for (int cg = 0; cg < 4; ++cg) {
      #pragma unroll
      for (int q = 0; q < 4; ++q)
        ob[((g << 4) + (lc << 2) + q) * 64 + (cg << 4) + lr] = bf16_rne(acc[g][cg][q]);
    }
    float v = lsum[g];
    v += __shfl_xor(v, 16, 64);
    v += __shfl_xor(v, 32, 64);
    if (lane < 16) lp[(size_t)((p << 2) + wave) * N + i0 + (g << 4) + lane] = v;
  }
}

// ---------------- K5: out = sum_p O_p / sum_p l_p (8 outs/thread) ----------
__global__ __launch_bounds__(256) void k_combine(
    const uint16_t* __restrict__ Op, const float* __restrict__ lp,
    float* __restrict__ out, int NP) {
  int idx = blockIdx.x * 256 + threadIdx.x;   // 131072 threads, 8 f32 each
  int n = idx >> 5;
  int c8 = (idx & 31) << 3;
  int h = c8 >> 6, o = c8 & 63;
  float s[8] = {0, 0, 0, 0, 0, 0, 0, 0};
  float ls = 0.f;
  for (int p = 0; p < NP; ++p) {
    size_t base = (size_t)((p << 2) + h) * 4096 + n;
    s8 v = *(const s8*)(Op + base * 64 + o);
    #pragma unroll
    for (int k = 0; k < 8; ++k) s[k] += bf2f((uint16_t)v[k]);
    ls += lp[base];
  }
  float inv = (ls > 0.f) ? 1.0f / ls : 0.f;
  f4 r0 = {s[0] * inv, s[1] * inv, s[2] * inv, s[3] * inv};
  f4 r1 = {s[4] * inv, s[5] * inv, s[6] * inv, s[7] * inv};
  float* dst = out + (size_t)n * 256 + c8;
  *(f4*)dst = r0;
  *(f4*)(dst + 4) = r1;
}

extern "C" void kernel_launch(void* const* d_in, const int* in_sizes, int n_in,
                              void* d_out, int out_size, void* d_ws, size_t ws_size,
                              hipStream_t stream) {
  (void)in_sizes; (void)n_in; (void)out_size;
  const float* x   = (const float*)d_in[0];
  const int*   adj = (const int*)d_in[1];
  const float* W   = (const float*)d_in[2];
  const float* a   = (const float*)d_in[3];
  float* out = (float*)d_out;
  char* ws = (char*)d_ws;

  size_t oWT = 0;
  size_t oHT = oWT + 131072;      // WT: 4*64*256*2
  size_t oF1 = oHT + 2097152;     // hT: 4*64*4096*2
  size_t oF2 = oF1 + 65536;       // f1: 4*4096*4
  size_t oFM = oF2 + 65536;       // f2
  size_t oOP = (oFM + 16 + 255) & ~(size_t)255;

  int NP = 8;
  while (NP > 1 && oOP + (size_t)NP * (2097152 + 65536) > ws_size) NP >>= 1;
  size_t oLP = oOP + (size_t)NP * 2097152;

  uint16_t* WT   = (uint16_t*)(ws + oWT);
  uint16_t* hT   = (uint16_t*)(ws + oHT);
  float*    f1   = (float*)(ws + oF1);
  float*    f2   = (float*)(ws + oF2);
  uint32_t* f2mk = (uint32_t*)(ws + oFM);
  uint16_t* Op   = (uint16_t*)(ws + oOP);
  float*    lp   = (float*)(ws + oLP);

  k_prep_wt<<<64, 256, 0, stream>>>(W, WT, f2mk);
  k_gemm_h<<<256, 256, 0, stream>>>(x, WT, a, hT, f1, f2, f2mk);
  k_attn<<<128 * NP, 256, 0, stream>>>(adj, f1, f2, f2mk, hT, Op, lp, NP);
  k_combine<<<512, 256, 0, stream>>>(Op, lp, out, NP);
}

// Round 3
// 62.901 us; speedup vs baseline: 1.5746x; 1.5746x over previous
//
#include <hip/hip_runtime.h>
#include <hip/hip_bf16.h>
#include <stdint.h>

#define LOG2E 1.4426950408889634f

typedef __attribute__((ext_vector_type(4))) float f4;
typedef __attribute__((ext_vector_type(4))) int   i4;
typedef __attribute__((ext_vector_type(8))) short s8;   // 8 x bf16
typedef __attribute__((ext_vector_type(4))) short s4;   // 4 x bf16

#if defined(__has_builtin)
# if __has_builtin(__builtin_amdgcn_exp2f)
#  define EXP2F(x) __builtin_amdgcn_exp2f(x)
# else
#  define EXP2F(x) exp2f(x)
# endif
#else
# define EXP2F(x) exp2f(x)
#endif

static __device__ __forceinline__ uint32_t fbits(float f) {
  union { float f; uint32_t u; } c; c.f = f; return c.u;
}
static __device__ __forceinline__ float ubits(uint32_t u) {
  union { uint32_t u; float f; } c; c.u = u; return c.f;
}
static __device__ __forceinline__ uint16_t bf16_rne(float f) {
  uint32_t b = fbits(f);
  b += 0x7FFFu + ((b >> 16) & 1u);
  return (uint16_t)(b >> 16);
}
static __device__ __forceinline__ float bf2f(uint16_t u) {
  return ubits(((uint32_t)u) << 16);
}
// order-preserving float->uint key (for atomicMax on floats)
static __device__ __forceinline__ uint32_t fkey(float f) {
  uint32_t u = fbits(f);
  return (u >> 31) ? ~u : (u | 0x80000000u);
}
static __device__ __forceinline__ float unkey(uint32_t k) {
  return ubits((k & 0x80000000u) ? (k ^ 0x80000000u) : ~k);
}

// ---- K1: W (H,256,64) f32 -> WT (H,64,256) bf16; init f2max keys ----
__global__ __launch_bounds__(256) void k_prep_wt(const float* __restrict__ W,
                                                 uint16_t* __restrict__ WT,
                                                 uint32_t* __restrict__ f2mkey) {
  if (blockIdx.x == 0 && threadIdx.x < 4) f2mkey[threadIdx.x] = 0u;
  int idx = (blockIdx.x * 256 + threadIdx.x) * 4;   // 65536 elems, grid 64
  f4 w = *(const f4*)(W + idx);
  int h = idx >> 14;
  int k = (idx >> 6) & 255;
  int o = idx & 63;
  uint16_t* base = WT + ((h << 6) + o) * 256 + k;
  base[0]   = bf16_rne(w.x);
  base[256] = bf16_rne(w.y);
  base[512] = bf16_rne(w.z);
  base[768] = bf16_rne(w.w);
}

// ------- K2: h = x @ W per head (MFMA), fused f1/f2 + f2max ---------------
// h stored directly in MFMA B-fragment order:
//   hTf chunk idx = ((head*32 + j/128)*4 + (j/32)%4)*4 + cg, 512 shorts/chunk;
//   within chunk lane l' = ((j%32)>>3)*16 + (o&15) holds elems e = j&7.
__global__ __launch_bounds__(256) void k_gemm_h(
    const float* __restrict__ x, const uint16_t* __restrict__ WT,
    const float* __restrict__ a,
    uint16_t* __restrict__ hTf, float* __restrict__ f1, float* __restrict__ f2,
    uint32_t* __restrict__ f2mkey) {
  const int N = 4096, K = 256;
  __shared__ uint16_t xs[16][264];
  int t = threadIdx.x;
  int i0 = blockIdx.x * 16;
  {
    int r = t >> 4, c = (t & 15) << 4;
    const float* src = x + (i0 + r) * K + c;
    union { uint16_t u[16]; s8 v[2]; } tmp;
    #pragma unroll
    for (int i = 0; i < 16; i += 4) {
      f4 v = *(const f4*)(src + i);
      tmp.u[i+0] = bf16_rne(v.x); tmp.u[i+1] = bf16_rne(v.y);
      tmp.u[i+2] = bf16_rne(v.z); tmp.u[i+3] = bf16_rne(v.w);
    }
    *(s8*)&xs[r][c]     = tmp.v[0];
    *(s8*)&xs[r][c + 8] = tmp.v[1];
  }
  __syncthreads();
  int wave = t >> 6, lane = t & 63, lr = lane & 15, lc = lane >> 4;
  f4 acc[4];
  #pragma unroll
  for (int cg = 0; cg < 4; ++cg) acc[cg] = (f4){0.f, 0.f, 0.f, 0.f};
  #pragma unroll
  for (int ks = 0; ks < 8; ++ks) {
    s8 af = *(const s8*)&xs[lr][ks * 32 + lc * 8];
    #pragma unroll
    for (int cg = 0; cg < 4; ++cg) {
      s8 bf = *(const s8*)(WT + ((wave << 6) + (cg << 4) + lr) * 256 + ks * 32 + lc * 8);
      acc[cg] = __builtin_amdgcn_mfma_f32_16x16x32_bf16(af, bf, acc[cg], 0, 0, 0);
    }
  }
  float p1[4] = {0, 0, 0, 0}, p2[4] = {0, 0, 0, 0};
  #pragma unroll
  for (int cg = 0; cg < 4; ++cg) {
    float a1v = a[wave * 128 + (cg << 4) + lr];
    float a2v = a[wave * 128 + 64 + (cg << 4) + lr];
    #pragma unroll
    for (int q = 0; q < 4; ++q) {
      p1[q] = fmaf(acc[cg][q], a1v, p1[q]);
      p2[q] = fmaf(acc[cg][q], a2v, p2[q]);
    }
  }
  #pragma unroll
  for (int m = 1; m <= 8; m <<= 1) {
    #pragma unroll
    for (int q = 0; q < 4; ++q) {
      p1[q] += __shfl_xor(p1[q], m, 64);
      p2[q] += __shfl_xor(p2[q], m, 64);
    }
  }
  if (lr == 0) {
    #pragma unroll
    for (int q = 0; q < 4; ++q) {
      f1[wave * N + i0 + (lc << 2) + q] = p1[q];
      f2[wave * N + i0 + (lc << 2) + q] = p2[q];
    }
  }
  // fused per-head f2 max -> atomicMax on order-preserving key
  float wm = fmaxf(fmaxf(p2[0], p2[1]), fmaxf(p2[2], p2[3]));
  wm = fmaxf(wm, __shfl_xor(wm, 16, 64));
  wm = fmaxf(wm, __shfl_xor(wm, 32, 64));
  if (lane == 0) atomicMax(&f2mkey[wave], fkey(wm));
  // store h in B-fragment order (j = n plays the k-dim of the attention MFMA)
  int b0 = (i0 & 31) + (lc << 2);        // j_in_chunk for q=0
  int hi = b0 >> 3, e0 = b0 & 7;         // q=0..3 stay within one 8-elem group
  size_t cbase = ((size_t)(wave * 32 + (i0 >> 7)) * 4 + ((i0 >> 5) & 3)) << 2;
  #pragma unroll
  for (int cg = 0; cg < 4; ++cg) {
    union { uint16_t u[4]; s4 v; } h4;
    #pragma unroll
    for (int q = 0; q < 4; ++q) h4.u[q] = bf16_rne(acc[cg][q]);
    *(s4*)(hTf + ((cbase + cg) << 9) + ((hi << 4) + lr) * 8 + e0) = h4.v;
  }
}

// -------- K4: flash partial. adj DMA->LDS (xor-swizzled source), ----------
// -------- fragment-order hTf loads, lsum via ones-MFMA, 1 barrier/tile ----
__global__ __launch_bounds__(256, 4) void k_attn(
    const int* __restrict__ adj, const float* __restrict__ f1,
    const float* __restrict__ f2, const uint32_t* __restrict__ f2mkey,
    const uint16_t* __restrict__ hTf,
    uint16_t* __restrict__ Op, float* __restrict__ lp, int NP) {
  const int N = 4096;
  __shared__ int adjs[2][32][128];        // 32 KB, no pad (DMA dest is linear)
  int p = blockIdx.x % NP;                // partition == XCD (b%8) for L2 locality
  int rb = blockIdx.x / NP;
  int i0 = rb << 5;                       // 32 rows per block
  int jcount = N / NP, jbase = p * jcount, ntiles = jcount >> 7;  // 128-col tiles
  int t = threadIdx.x, wave = t >> 6, lane = t & 63, lr = lane & 15, lc = lane >> 4;

  float fm = unkey(f2mkey[wave]);
  float d1[2], d2[2];
  #pragma unroll
  for (int g = 0; g < 2; ++g) {
    float f1v = f1[wave * N + i0 + (g << 4) + lr];
    float s = f1v + fm;
    float M = fmaxf(s, 0.2f * s);          // static per-row upper bound
    d1[g] = fmaf(f1v, LOG2E, -M * LOG2E);
    d2[g] = fmaf(f1v, 0.2f * LOG2E, -M * LOG2E);
  }
  f4 acc[2][4], accl[2];
  #pragma unroll
  for (int g = 0; g < 2; ++g) {
    accl[g] = (f4){0.f, 0.f, 0.f, 0.f};
    #pragma unroll
    for (int cg = 0; cg < 4; ++cg) acc[g][cg] = (f4){0.f, 0.f, 0.f, 0.f};
  }
  const s8 ones = {0x3F80, 0x3F80, 0x3F80, 0x3F80, 0x3F80, 0x3F80, 0x3F80, 0x3F80};

  // staging geometry: wave w stages rows w*8..w*8+7, 2 rows (1 KB) per DMA inst
  int rloc = (wave << 3) + (lane >> 5);   // row for pair 0
  int chb = lane & 31;                    // LDS 16B-slot this lane fills
  const int* gbase = adj + (size_t)(i0 + rloc) * N + jbase;

  #define STAGE(TILE, BUF)                                                    \
    {                                                                         \
      int jc_ = (TILE) << 7;                                                  \
      _Pragma("unroll")                                                       \
      for (int pair = 0; pair < 4; ++pair) {                                  \
        int row_ = rloc + (pair << 1);                                        \
        int ch_ = chb ^ (row_ & 7);      /* pre-swizzled global source */     \
        const int* gp_ = gbase + (size_t)(pair << 1) * N + jc_ + (ch_ << 2);  \
        __builtin_amdgcn_global_load_lds(                                     \
            (const __attribute__((address_space(1))) void*)gp_,               \
            (__attribute__((address_space(3))) void*)                         \
                &adjs[BUF][(wave << 3) + (pair << 1)][0],                     \
            16, 0, 0);                                                        \
      }                                                                       \
    }

  const float* f2b = f2 + wave * N + jbase + (lc << 3);
  const uint16_t* hTfb = hTf + (((size_t)(wave * 32) + (jbase >> 7)) << 13) + lane * 8;

  STAGE(0, 0);
  __syncthreads();

  for (int tile = 0;; ++tile) {
    int cur = tile & 1;
    if (tile + 1 < ntiles) STAGE(tile + 1, cur ^ 1);   // DMA in flight under compute
    const uint16_t* hTft = hTfb + ((size_t)tile << 13);
    #pragma unroll
    for (int ks = 0; ks < 4; ++ks) {
      f4 f2v0 = *(const f4*)(f2b + (tile << 7) + (ks << 5));
      f4 f2v1 = *(const f4*)(f2b + (tile << 7) + (ks << 5) + 4);
      s8 bf[4];
      #pragma unroll
      for (int cg = 0; cg < 4; ++cg)
        bf[cg] = *(const s8*)(hTft + (((ks << 2) + cg) << 9));
      #pragma unroll
      for (int g = 0; g < 2; ++g) {
        const i4* rowp = (const i4*)&adjs[cur][(g << 4) + lr][0];
        int X = (ks << 3) + (lc << 1), s7 = lr & 7;
        i4 a0 = rowp[X ^ s7];             // swizzled slot holds chunk X
        i4 a1 = rowp[(X + 1) ^ s7];
        uint32_t eb[8];
        #pragma unroll
        for (int e = 0; e < 8; ++e) {
          float f2e = (e < 4) ? f2v0[e] : f2v1[e - 4];
          int   ai  = (e < 4) ? a0[e]   : a1[e - 4];
          float arg = fmaxf(fmaf(f2e, LOG2E, d1[g]),
                            fmaf(f2e, 0.2f * LOG2E, d2[g]));
          eb[e] = (fbits(EXP2F(arg)) & (uint32_t)(-ai)) + 0x8000u;  // mask, round
        }
        union { uint32_t u[4]; s8 v; } af;
        #pragma unroll
        for (int i2 = 0; i2 < 4; ++i2)
          af.u[i2] = __builtin_amdgcn_perm(eb[2 * i2 + 1], eb[2 * i2], 0x07060302u);
        #pragma unroll
        for (int cg = 0; cg < 4; ++cg)
          acc[g][cg] = __builtin_amdgcn_mfma_f32_16x16x32_bf16(af.v, bf[cg],
                                                               acc[g][cg], 0, 0, 0);
        accl[g] = __builtin_amdgcn_mfma_f32_16x16x32_bf16(af.v, ones, accl[g], 0, 0, 0);
      }
    }
    if (tile + 1 >= ntiles) break;
    __syncthreads();
  }
  #undef STAGE

  // store partials
  uint16_t* ob = Op + (size_t)((p << 2) + wave) * N * 64 + (size_t)i0 * 64;
  #pragma unroll
  for (int g = 0; g < 2; ++g) {
    #pragma unroll
    for (int cg = 0; cg < 4; ++cg) {
      #pragma unroll
      for (int q = 0; q < 4; ++q)
        ob[((g << 4) + (lc << 2) + q) * 64 + (cg << 4) + lr] = bf16_rne(acc[g][cg][q]);
    }
    if (lr == 0) {
      #pragma unroll
      for (int q = 0; q < 4; ++q)
        lp[(size_t)((p << 2) + wave) * N + i0 + (g << 4) + (lc << 2) + q] = accl[g][q];
    }
  }
}

// ---------------- K5: out = sum_p O_p / sum_p l_p (8 outs/thread) ----------
__global__ __launch_bounds__(256) void k_combine(
    const uint16_t* __restrict__ Op, const float* __restrict__ lp,
    float* __restrict__ out, int NP) {
  int idx = blockIdx.x * 256 + threadIdx.x;   // 131072 threads, 8 f32 each
  int n = idx >> 5;
  int c8 = (idx & 31) << 3;
  int h = c8 >> 6, o = c8 & 63;
  float s[8] = {0, 0, 0, 0, 0, 0, 0, 0};
  float ls = 0.f;
  for (int p = 0; p < NP; ++p) {
    size_t base = (size_t)((p << 2) + h) * 4096 + n;
    s8 v = *(const s8*)(Op + base * 64 + o);
    #pragma unroll
    for (int k = 0; k < 8; ++k) s[k] += bf2f((uint16_t)v[k]);
    ls += lp[base];
  }
  float inv = (ls > 0.f) ? 1.0f / ls : 0.f;
  f4 r0 = {s[0] * inv, s[1] * inv, s[2] * inv, s[3] * inv};
  f4 r1 = {s[4] * inv, s[5] * inv, s[6] * inv, s[7] * inv};
  float* dst = out + (size_t)n * 256 + c8;
  *(f4*)dst = r0;
  *(f4*)(dst + 4) = r1;
}

extern "C" void kernel_launch(void* const* d_in, const int* in_sizes, int n_in,
                              void* d_out, int out_size, void* d_ws, size_t ws_size,
                              hipStream_t stream) {
  (void)in_sizes; (void)n_in; (void)out_size;
  const float* x   = (const float*)d_in[0];
  const int*   adj = (const int*)d_in[1];
  const float* W   = (const float*)d_in[2];
  const float* a   = (const float*)d_in[3];
  float* out = (float*)d_out;
  char* ws = (char*)d_ws;

  size_t oWT = 0;
  size_t oHT = oWT + 131072;      // WT: 4*64*256*2
  size_t oF1 = oHT + 2097152;     // hTf: 4*64*4096*2 (fragment order)
  size_t oF2 = oF1 + 65536;      // f1: 4*4096*4
  size_t oFM = oF2 + 65536;      // f2
  size_t oOP = (oFM + 16 + 255) & ~(size_t)255;

  int NP = 8;
  while (NP > 1 && oOP + (size_t)NP * (2097152 + 65536) > ws_size) NP >>= 1;
  size_t oLP = oOP + (size_t)NP * 2097152;

  uint16_t* WT   = (uint16_t*)(ws + oWT);
  uint16_t* hTf  = (uint16_t*)(ws + oHT);
  float*    f1   = (float*)(ws + oF1);
  float*    f2   = (float*)(ws + oF2);
  uint32_t* f2mk = (uint32_t*)(ws + oFM);
  uint16_t* Op   = (uint16_t*)(ws + oOP);
  float*    lp   = (float*)(ws + oLP);

  k_prep_wt<<<64, 256, 0, stream>>>(W, WT, f2mk);
  k_gemm_h<<<256, 256, 0, stream>>>(x, WT, a, hTf, f1, f2, f2mk);
  k_attn<<<128 * NP, 256, 0, stream>>>(adj, f1, f2, f2mk, hTf, Op, lp, NP);
  k_combine<<<512, 256, 0, stream>>>(Op, lp, out, NP);
}